// Round 3
// baseline (1407.088 us; speedup 1.0000x reference)
//
#include <hip/hip_runtime.h>

typedef unsigned short u16;
typedef short s16x4 __attribute__((ext_vector_type(4)));
typedef short s16x8 __attribute__((ext_vector_type(8)));
typedef float f32x4 __attribute__((ext_vector_type(4)));

#define DEVFN __device__ __forceinline__

// problem constants
constexpr long AW_OFF  = 4194304;               // attn_output elems (2*2048*1024)
constexpr long PAT_OFF = AW_OFF + 134217728;    // + attn_weights elems (2*16*2048*2048)

DEVFN u16 f2bf(float x) {
  unsigned u = __builtin_bit_cast(unsigned, x);
  unsigned r = (u + 0x7fffu + ((u >> 16) & 1u)) >> 16;   // RNE
  return (u16)r;
}

DEVFN void gld16(const u16* g, u16* l) {
  __builtin_amdgcn_global_load_lds(
      (const __attribute__((address_space(1))) unsigned int*)g,
      (__attribute__((address_space(3))) unsigned int*)l, 16, 0, 0);
}

DEVFN s16x8 ld_frag(const u16* p) {
  s16x4 lo = *(const s16x4*)p;
  s16x4 hi = *(const s16x4*)(p + 16);
  s16x8 r;
  r[0] = lo[0]; r[1] = lo[1]; r[2] = lo[2]; r[3] = lo[3];
  r[4] = hi[0]; r[5] = hi[1]; r[6] = hi[2]; r[7] = hi[3];
  return r;
}

// ---------------- fp32 -> bf16 elementwise ----------------
__global__ __launch_bounds__(256) void k_cvt(const float* __restrict__ in,
                                             u16* __restrict__ out, int n4) {
  int i = blockIdx.x * 256 + threadIdx.x;
  if (i >= n4) return;
  float4 v = ((const float4*)in)[i];
  s16x4 o; o[0] = f2bf(v.x); o[1] = f2bf(v.y); o[2] = f2bf(v.z); o[3] = f2bf(v.w);
  ((s16x4*)out)[i] = o;
}

// ---------------- tiled transpose: out[n][k] = bf16(in[k][n]) ----------------
template <bool IN_F32>
__global__ __launch_bounds__(256) void k_tr(const void* __restrict__ inv,
                                            u16* __restrict__ out,
                                            long ldin, long ldout,
                                            long inz1, long inz2, long outz, int zdiv) {
  __shared__ u16 tile[32][33];
  int z = blockIdx.z;
  long ioff = (long)(z / zdiv) * inz1 + (long)(z % zdiv) * inz2;
  int k0 = blockIdx.y * 32, n0 = blockIdx.x * 32;
  int tx = threadIdx.x, ty = threadIdx.y;
#pragma unroll
  for (int i = 0; i < 4; ++i) {
    long k = k0 + ty + i * 8, n = n0 + tx;
    u16 v;
    if constexpr (IN_F32) v = f2bf(((const float*)inv)[ioff + k * ldin + n]);
    else                  v = ((const u16*)inv)[ioff + k * ldin + n];
    tile[ty + i * 8][tx] = v;
  }
  __syncthreads();
  long ooff = (long)z * outz;
#pragma unroll
  for (int i = 0; i < 4; ++i) {
    long n = n0 + ty + i * 8, k = k0 + tx;
    out[ooff + n * ldout + k] = tile[tx][ty + i * 8];
  }
}

// ---------------- batched NT GEMM: C = f(alpha * A[M,K] @ B[N,K]^T) ----------------
// EPI 0: v = alpha*acc + bias[col];  EPI 1: v = exp(alpha*acc) * rinv[z][row]
// global_load_lds staging (m97 structure), linear LDS, 128x128 tile, BK=64, 4 waves.
template <typename OutT, int EPI>
__global__ __launch_bounds__(256) void k_gemm_nt(
    const u16* __restrict__ Ap, const u16* __restrict__ Bp, OutT* __restrict__ Cp,
    const float* __restrict__ bias, const float* __restrict__ rinv, float alpha, int K,
    long lda, long ldb, long ldc,
    long saz1, long saz2, long sbz1, long sbz2, long scz1, long scz2,
    long sbias, int zdiv) {
  __shared__ __align__(16) u16 At[128][64];
  __shared__ __align__(16) u16 Bt[128][64];
  const int tid = threadIdx.x, lane = tid & 63, wid = tid >> 6;
  const int wm = wid >> 1, wn = wid & 1;
  const int z = blockIdx.z, z1 = z / zdiv, z2 = z % zdiv;
  const u16* Ab = Ap + (long)z1 * saz1 + (long)z2 * saz2;
  const u16* Bb = Bp + (long)z1 * sbz1 + (long)z2 * sbz2;
  OutT* C = Cp + (long)z1 * scz1 + (long)z2 * scz2;
  const float* bz = bias ? bias + (long)z * sbias : nullptr;
  const int row0 = blockIdx.y * 128, col0 = blockIdx.x * 128;
  const int sr = lane >> 3, sc = (lane & 7) * 8;

  f32x4 acc[4][4] = {};

  for (int k0 = 0; k0 < K; k0 += 64) {
#pragma unroll
    for (int i = 0; i < 4; ++i) {
      const int rr = (wid * 4 + i) * 8 + sr;
      gld16(Ab + (long)(row0 + rr) * lda + (k0 + sc), &At[rr][sc]);
      gld16(Bb + (long)(col0 + rr) * ldb + (k0 + sc), &Bt[rr][sc]);
    }
    __syncthreads();
#pragma unroll
    for (int kk = 0; kk < 2; ++kk) {
      const int kg = kk * 32 + ((lane >> 4) << 2);
      s16x8 af[4], bf[4];
#pragma unroll
      for (int m = 0; m < 4; ++m) af[m] = ld_frag(&At[wm * 64 + m * 16 + (lane & 15)][kg]);
#pragma unroll
      for (int n = 0; n < 4; ++n) bf[n] = ld_frag(&Bt[wn * 64 + n * 16 + (lane & 15)][kg]);
#pragma unroll
      for (int m = 0; m < 4; ++m)
#pragma unroll
        for (int n = 0; n < 4; ++n)
          acc[m][n] = __builtin_amdgcn_mfma_f32_16x16x32_bf16(af[m], bf[n], acc[m][n], 0, 0, 0);
    }
    __syncthreads();
  }

  const float* rz = (EPI == 1) ? rinv + (long)z * 2048 : nullptr;
#pragma unroll
  for (int m = 0; m < 4; ++m) {
    const int grow = row0 + wm * 64 + m * 16 + ((lane >> 4) << 2);
#pragma unroll
    for (int r = 0; r < 4; ++r) {
      float iv = 0.0f;
      if constexpr (EPI == 1) iv = rz[grow + r];
#pragma unroll
      for (int n = 0; n < 4; ++n) {
        const int gcol = col0 + wn * 64 + n * 16 + (lane & 15);
        float v;
        if constexpr (EPI == 1) v = __expf(alpha * acc[m][n][r]) * iv;
        else                    v = alpha * acc[m][n][r] + (bz ? bz[gcol] : 0.0f);
        if constexpr (sizeof(OutT) == 2) C[(long)(grow + r) * ldc + gcol] = f2bf(v);
        else                             C[(long)(grow + r) * ldc + gcol] = v;
      }
    }
  }
}

// ---------------- flash attention: ctx[b,s,h*64+d], rinv[bh,q] = 1/sum(exp) ----------------
// grid (S/128, B*H); 4 waves: wk = wid>>1 (k-half), wq = wid&1 (q-half).
// St[k][q] via mfma(K,Q) so P rows feed PV's B operand directly from registers.
__global__ __launch_bounds__(256) void k_flash(
    const u16* __restrict__ qp, const u16* __restrict__ kp, const u16* __restrict__ vt,
    u16* __restrict__ ctx, float* __restrict__ rinv) {
  __shared__ __align__(16) char lds[49152];
  u16* Qt = (u16*)lds;            // [128][64]
  u16* Kt = (u16*)(lds + 16384);  // [128][64]
  u16* Vl = (u16*)(lds + 32768);  // [64][128]
  const int tid = threadIdx.x, lane = tid & 63, wid = tid >> 6;
  const int wk = wid >> 1, wq = wid & 1;
  const int bh = blockIdx.y, q0 = blockIdx.x * 128;
  const long qkbase = (long)(bh >> 4) * 2097152 + (long)(bh & 15) * 64;
  const long vbase = (long)bh * 131072;
  const int sr = lane >> 3, sc = (lane & 7) * 8;
  const int vr = lane >> 4, vc = (lane & 15) * 8;

#pragma unroll
  for (int i = 0; i < 4; ++i) {
    const int rr = (wid * 4 + i) * 8 + sr;
    gld16(qp + qkbase + (long)(q0 + rr) * 1024 + sc, Qt + rr * 64 + sc);
  }
  __syncthreads();

  s16x8 qf[2][4];
#pragma unroll
  for (int kk = 0; kk < 2; ++kk) {
    const int kg = kk * 32 + ((lane >> 4) << 2);
#pragma unroll
    for (int nq = 0; nq < 4; ++nq)
      qf[kk][nq] = ld_frag(Qt + (wq * 64 + nq * 16 + (lane & 15)) * 64 + kg);
  }

  f32x4 cacc[4][4] = {};
  float rs[4] = {0.f, 0.f, 0.f, 0.f};

  for (int t = 0; t < 16; ++t) {
    const int kb = t * 128;
#pragma unroll
    for (int i = 0; i < 4; ++i) {
      const int rr = (wid * 4 + i) * 8 + sr;
      gld16(kp + qkbase + (long)(kb + rr) * 1024 + sc, Kt + rr * 64 + sc);
      const int dd = (wid * 4 + i) * 4 + vr;
      gld16(vt + vbase + (long)dd * 2048 + (kb + vc), Vl + dd * 128 + vc);
    }
    __syncthreads();

    f32x4 st[4][4] = {};
#pragma unroll
    for (int kk = 0; kk < 2; ++kk) {
      const int kg = kk * 32 + ((lane >> 4) << 2);
      s16x8 af[4];
#pragma unroll
      for (int mk = 0; mk < 4; ++mk)
        af[mk] = ld_frag(Kt + (wk * 64 + mk * 16 + (lane & 15)) * 64 + kg);
#pragma unroll
      for (int mk = 0; mk < 4; ++mk)
#pragma unroll
        for (int nq = 0; nq < 4; ++nq)
          st[mk][nq] = __builtin_amdgcn_mfma_f32_16x16x32_bf16(af[mk], qf[kk][nq], st[mk][nq], 0, 0, 0);
    }
#pragma unroll
    for (int mk = 0; mk < 4; ++mk)
#pragma unroll
      for (int nq = 0; nq < 4; ++nq)
#pragma unroll
        for (int j = 0; j < 4; ++j) {
          const float p = __expf(st[mk][nq][j] * 0.125f);
          st[mk][nq][j] = p;
          rs[nq] += p;
        }
#pragma unroll
    for (int ks = 0; ks < 2; ++ks) {
      const int kg2 = ks * 32 + ((lane >> 4) << 2);
      s16x8 pb[4];
#pragma unroll
      for (int nq = 0; nq < 4; ++nq) {
        s16x8 b;
#pragma unroll
        for (int j = 0; j < 4; ++j) {
          b[j]     = (short)f2bf(st[2 * ks][nq][j]);
          b[4 + j] = (short)f2bf(st[2 * ks + 1][nq][j]);
        }
        pb[nq] = b;
      }
#pragma unroll
      for (int md = 0; md < 4; ++md) {
        const s16x8 vf = ld_frag(Vl + (md * 16 + (lane & 15)) * 128 + wk * 64 + kg2);
#pragma unroll
        for (int nq = 0; nq < 4; ++nq)
          cacc[md][nq] = __builtin_amdgcn_mfma_f32_16x16x32_bf16(vf, pb[nq], cacc[md][nq], 0, 0, 0);
      }
    }
    __syncthreads();
  }

#pragma unroll
  for (int nq = 0; nq < 4; ++nq) {
    rs[nq] += __shfl_xor(rs[nq], 16, 64);
    rs[nq] += __shfl_xor(rs[nq], 32, 64);
  }
  float* ctxl = (float*)lds;            // [64][129]
  float* rsl  = (float*)(lds + 33024);  // [128]
  if (wk == 1) {
#pragma unroll
    for (int md = 0; md < 4; ++md)
#pragma unroll
      for (int nq = 0; nq < 4; ++nq)
#pragma unroll
        for (int r = 0; r < 4; ++r)
          ctxl[(md * 16 + ((lane >> 4) << 2) + r) * 129 + wq * 64 + nq * 16 + (lane & 15)] = cacc[md][nq][r];
    if (lane < 16)
#pragma unroll
      for (int nq = 0; nq < 4; ++nq) rsl[wq * 64 + nq * 16 + lane] = rs[nq];
  }
  __syncthreads();
  if (wk == 0) {
#pragma unroll
    for (int md = 0; md < 4; ++md)
#pragma unroll
      for (int nq = 0; nq < 4; ++nq)
#pragma unroll
        for (int r = 0; r < 4; ++r) {
          const int idx = (md * 16 + ((lane >> 4) << 2) + r) * 129 + wq * 64 + nq * 16 + (lane & 15);
          ctxl[idx] += cacc[md][nq][r];
        }
    if (lane < 16)
#pragma unroll
      for (int nq = 0; nq < 4; ++nq) {
        const int qi = wq * 64 + nq * 16 + lane;
        const float inv = 1.0f / (rsl[qi] + rs[nq]);
        rsl[qi] = inv;
        rinv[(long)bh * 2048 + q0 + qi] = inv;
      }
  }
  __syncthreads();
  // cooperative transposed write: ctx[b][q0+qr][h*64 + d]
  const int qr = tid >> 1, half = tid & 1;
  const float inv = rsl[qr];
  u16* dst = ctx + (long)(bh >> 4) * 2097152 + (long)(q0 + qr) * 1024 + (long)(bh & 15) * 64 + half * 32;
#pragma unroll
  for (int c = 0; c < 4; ++c) {
    s16x8 o;
#pragma unroll
    for (int j = 0; j < 8; ++j) {
      const int d = half * 32 + c * 8 + j;
      o[j] = (short)f2bf(ctxl[d * 129 + qr] * inv);
    }
    ((s16x8*)dst)[c] = o;
  }
}

// ---------------- in-place row softmax, rows of 2048 fp32 ----------------
__global__ __launch_bounds__(256) void k_softmax(float* __restrict__ base) {
  float* p = base + (long)blockIdx.x * 2048;
  const int t = threadIdx.x;
  float4 v0 = ((const float4*)p)[t];
  float4 v1 = ((const float4*)p)[t + 256];
  float m = fmaxf(fmaxf(fmaxf(v0.x, v0.y), fmaxf(v0.z, v0.w)),
                  fmaxf(fmaxf(v1.x, v1.y), fmaxf(v1.z, v1.w)));
#pragma unroll
  for (int i = 32; i >= 1; i >>= 1) m = fmaxf(m, __shfl_xor(m, i, 64));
  __shared__ float sm[4], ss[4];
  if ((t & 63) == 0) sm[t >> 6] = m;
  __syncthreads();
  m = fmaxf(fmaxf(sm[0], sm[1]), fmaxf(sm[2], sm[3]));
  float4 e0, e1;
  e0.x = __expf(v0.x - m); e0.y = __expf(v0.y - m); e0.z = __expf(v0.z - m); e0.w = __expf(v0.w - m);
  e1.x = __expf(v1.x - m); e1.y = __expf(v1.y - m); e1.z = __expf(v1.z - m); e1.w = __expf(v1.w - m);
  float s = (e0.x + e0.y + e0.z + e0.w) + (e1.x + e1.y + e1.z + e1.w);
#pragma unroll
  for (int i = 32; i >= 1; i >>= 1) s += __shfl_xor(s, i, 64);
  if ((t & 63) == 0) ss[t >> 6] = s;
  __syncthreads();
  s = ss[0] + ss[1] + ss[2] + ss[3];
  float inv = 1.0f / s;
  e0.x *= inv; e0.y *= inv; e0.z *= inv; e0.w *= inv;
  e1.x *= inv; e1.y *= inv; e1.z *= inv; e1.w *= inv;
  ((float4*)p)[t] = e0;
  ((float4*)p)[t + 256] = e1;
}

// ---------------- launch ----------------
extern "C" void kernel_launch(void* const* d_in, const int* in_sizes, int n_in,
                              void* d_out, int out_size, void* d_ws, size_t ws_size,
                              hipStream_t stream) {
  const float* query = (const float*)d_in[0];
  const float* key   = (const float*)d_in[1];
  const float* value = (const float*)d_in[2];
  const float* Wq = (const float*)d_in[3];
  const float* bq = (const float*)d_in[4];
  const float* Wk = (const float*)d_in[5];
  const float* bk = (const float*)d_in[6];
  const float* Wv = (const float*)d_in[7];
  const float* bv = (const float*)d_in[8];
  const float* Wo = (const float*)d_in[9];
  const float* bo = (const float*)d_in[10];
  const float* Wa = (const float*)d_in[11];
  const float* ba = (const float*)d_in[12];
  float* out = (float*)d_out;
  char* ws = (char*)d_ws;

  // workspace layout (bytes)
  u16* qb  = (u16*)(ws + 0);           // [4096,1024] bf16 query
  u16* kb  = (u16*)(ws + 8388608);
  u16* vb  = (u16*)(ws + 16777216);
  u16* Wqt = (u16*)(ws + 25165824);    // [1024,1024] W^T bf16 (reused as rinv later)
  u16* Wkt = (u16*)(ws + 27262976);
  u16* Wvt = (u16*)(ws + 29360128);
  u16* Wot = (u16*)(ws + 31457280);
  u16* Wat = (u16*)(ws + 33554432);    // [3,1024,1024]
  u16* qp  = (u16*)(ws + 39845888);    // [4096,1024] projected q
  u16* kp  = (u16*)(ws + 48234496);
  u16* vp  = (u16*)(ws + 56623104);
  u16* vt  = (u16*)(ws + 65011712);    // [B,H,64,2048] V^T per head
  u16* ctx = (u16*)(ws + 73400320);    // [4096,1024]
  u16* qa  = (u16*)(ws + 81788928);    // [3,4096,1024] aspect q
  u16* ka  = (u16*)(ws + 106954752);   // [3,4096,1024] aspect k
  float* rinv = (float*)(ws + 25165824);  // [32,2048] (overwrites Wqt after use)

  dim3 b256(256);
  dim3 trb(32, 8);

  // bf16 conversions of activations
  k_cvt<<<4096, b256, 0, stream>>>(query, qb, 1048576);
  k_cvt<<<4096, b256, 0, stream>>>(key,   kb, 1048576);
  k_cvt<<<4096, b256, 0, stream>>>(value, vb, 1048576);

  // weight transposes (fp32 -> bf16, [N,K])
  k_tr<true><<<dim3(32, 32, 1), trb, 0, stream>>>(Wq, Wqt, 1024, 1024, 0, 0, 0, 1);
  k_tr<true><<<dim3(32, 32, 1), trb, 0, stream>>>(Wk, Wkt, 1024, 1024, 0, 0, 0, 1);
  k_tr<true><<<dim3(32, 32, 1), trb, 0, stream>>>(Wv, Wvt, 1024, 1024, 0, 0, 0, 1);
  k_tr<true><<<dim3(32, 32, 1), trb, 0, stream>>>(Wo, Wot, 1024, 1024, 0, 0, 0, 1);
  k_tr<true><<<dim3(32, 32, 3), trb, 0, stream>>>(Wa, Wat, 1024, 1024, 0, 1048576, 1048576, 3);

  // Q/K/V projections -> bf16 [4096,1024]   (Q first: frees Wqt slot for rinv)
  k_gemm_nt<u16, 0><<<dim3(8, 32, 1), b256, 0, stream>>>(
      qb, Wqt, qp, bq, nullptr, 1.0f, 1024, 1024, 1024, 1024, 0, 0, 0, 0, 0, 0, 0, 1);
  k_gemm_nt<u16, 0><<<dim3(8, 32, 1), b256, 0, stream>>>(
      kb, Wkt, kp, bk, nullptr, 1.0f, 1024, 1024, 1024, 1024, 0, 0, 0, 0, 0, 0, 0, 1);
  k_gemm_nt<u16, 0><<<dim3(8, 32, 1), b256, 0, stream>>>(
      vb, Wvt, vp, bv, nullptr, 1.0f, 1024, 1024, 1024, 1024, 0, 0, 0, 0, 0, 0, 0, 1);

  // aspect projections, z = aspect (3)
  k_gemm_nt<u16, 0><<<dim3(8, 32, 3), b256, 0, stream>>>(
      qb, Wat, qa, ba, nullptr, 1.0f, 1024, 1024, 1024, 1024,
      0, 0, 0, 1048576, 0, 4194304, 1024, 3);
  k_gemm_nt<u16, 0><<<dim3(8, 32, 3), b256, 0, stream>>>(
      kb, Wat, ka, ba, nullptr, 1.0f, 1024, 1024, 1024, 1024,
      0, 0, 0, 1048576, 0, 4194304, 1024, 3);

  // per-head V^T: vt[b,h][d][s]  (z = b*16+h)
  k_tr<false><<<dim3(2, 64, 32), trb, 0, stream>>>(
      vp, vt, 1024, 2048, 2097152, 64, 131072, 16);

  // flash attention: ctx (bf16) + rinv
  k_flash<<<dim3(16, 32), b256, 0, stream>>>(qp, kp, vt, ctx, rinv);

  // attn_weights = exp(QK^T * scale) * rinv  -> d_out (single write pass)
  k_gemm_nt<float, 1><<<dim3(16, 16, 32), b256, 0, stream>>>(
      qp, kp, out + AW_OFF, nullptr, rinv, 0.125f, 64, 1024, 1024, 2048,
      2097152, 64, 2097152, 64, 67108864, 4194304, 0, 16);

  // full-dim pattern logits -> d_out patterns region (z = a*2+b)
  k_gemm_nt<float, 0><<<dim3(16, 16, 6), b256, 0, stream>>>(
      qa, ka, out + PAT_OFF, nullptr, nullptr, 0.125f, 1024, 1024, 1024, 2048,
      0, 2097152, 0, 2097152, 0, 4194304, 0, 6);

  // softmax over patterns only (3*B*S = 12288 rows of 2048)
  k_softmax<<<12288, b256, 0, stream>>>(out + PAT_OFF);

  // output projection -> d_out attn_output
  k_gemm_nt<float, 0><<<dim3(8, 32, 1), b256, 0, stream>>>(
      ctx, Wot, out, bo, nullptr, 1.0f, 1024, 1024, 1024, 1024, 0, 0, 0, 0, 0, 0, 0, 1);
}

// Round 4
// 564.313 us; speedup vs baseline: 2.4935x; 2.4935x over previous
//
#include <hip/hip_runtime.h>

typedef unsigned short u16;
typedef short s16x4 __attribute__((ext_vector_type(4)));
typedef short s16x8 __attribute__((ext_vector_type(8)));
typedef float f32x4 __attribute__((ext_vector_type(4)));

#define DEVFN __device__ __forceinline__

// problem constants
constexpr long AW_OFF  = 4194304;               // attn_output elems (2*2048*1024)
constexpr long PAT_OFF = AW_OFF + 134217728;    // + attn_weights elems (2*16*2048*2048)

DEVFN u16 f2bf(float x) {
  unsigned u = __builtin_bit_cast(unsigned, x);
  unsigned r = (u + 0x7fffu + ((u >> 16) & 1u)) >> 16;   // RNE
  return (u16)r;
}

DEVFN void gld16(const u16* g, u16* l) {
  __builtin_amdgcn_global_load_lds(
      (const __attribute__((address_space(1))) unsigned int*)g,
      (__attribute__((address_space(3))) unsigned int*)l, 16, 0, 0);
}

// ---------------- fp32 -> bf16 elementwise ----------------
__global__ __launch_bounds__(256) void k_cvt(const float* __restrict__ in,
                                             u16* __restrict__ out, int n4) {
  int i = blockIdx.x * 256 + threadIdx.x;
  if (i >= n4) return;
  float4 v = ((const float4*)in)[i];
  s16x4 o; o[0] = f2bf(v.x); o[1] = f2bf(v.y); o[2] = f2bf(v.z); o[3] = f2bf(v.w);
  ((s16x4*)out)[i] = o;
}

// ---------------- tiled transpose: out[n][k] = bf16(in[k][n]) ----------------
template <bool IN_F32>
__global__ __launch_bounds__(256) void k_tr(const void* __restrict__ inv,
                                            u16* __restrict__ out,
                                            long ldin, long ldout,
                                            long inz1, long inz2, long outz, int zdiv) {
  __shared__ u16 tile[32][33];
  int z = blockIdx.z;
  long ioff = (long)(z / zdiv) * inz1 + (long)(z % zdiv) * inz2;
  int k0 = blockIdx.y * 32, n0 = blockIdx.x * 32;
  int tx = threadIdx.x, ty = threadIdx.y;
#pragma unroll
  for (int i = 0; i < 4; ++i) {
    long k = k0 + ty + i * 8, n = n0 + tx;
    u16 v;
    if constexpr (IN_F32) v = f2bf(((const float*)inv)[ioff + k * ldin + n]);
    else                  v = ((const u16*)inv)[ioff + k * ldin + n];
    tile[ty + i * 8][tx] = v;
  }
  __syncthreads();
  long ooff = (long)z * outz;
#pragma unroll
  for (int i = 0; i < 4; ++i) {
    long n = n0 + ty + i * 8, k = k0 + tx;
    out[ooff + n * ldout + k] = tile[tx][ty + i * 8];
  }
}

// ---------------- batched NT GEMM: C = f(alpha * A[M,K] @ B[N,K]^T) ----------------
// EPI 0: v = alpha*acc + bias[col];  EPI 1: v = exp(alpha*acc) * rinv[z][row]
// global_load_lds staging, LINEAR LDS dest + XOR-swizzled (p = c ^ (row&7), 16B units)
// global source and fragment reads -> conflict-free ds_read_b128 fragments.
// Fragments use contiguous-k8 per lane (same bijective k-permutation on A and B
// => dot product unchanged). 128x128 tile, BK=64, 4 waves.
template <typename OutT, int EPI>
__global__ __launch_bounds__(256) void k_gemm_nt(
    const u16* __restrict__ Ap, const u16* __restrict__ Bp, OutT* __restrict__ Cp,
    const float* __restrict__ bias, const float* __restrict__ rinv, float alpha, int K,
    long lda, long ldb, long ldc,
    long saz1, long saz2, long sbz1, long sbz2, long scz1, long scz2,
    long sbias, int zdiv) {
  __shared__ __align__(16) u16 At[128][64];
  __shared__ __align__(16) u16 Bt[128][64];
  const int tid = threadIdx.x, lane = tid & 63, wid = tid >> 6;
  const int wm = wid >> 1, wn = wid & 1;
  const int z = blockIdx.z, z1 = z / zdiv, z2 = z % zdiv;
  const u16* Ab = Ap + (long)z1 * saz1 + (long)z2 * saz2;
  const u16* Bb = Bp + (long)z1 * sbz1 + (long)z2 * sbz2;
  OutT* C = Cp + (long)z1 * scz1 + (long)z2 * scz2;
  const float* bz = bias ? bias + (long)z * sbias : nullptr;
  const int row0 = blockIdx.y * 128, col0 = blockIdx.x * 128;
  const int lk = lane & 15, g = lane >> 4;

  f32x4 acc[4][4] = {};

  for (int k0 = 0; k0 < K; k0 += 64) {
#pragma unroll
    for (int it = 0; it < 4; ++it) {
      const int u = it * 256 + tid;          // 16B-unit index over the tile
      const int r = u >> 3, p = u & 7;       // row, physical unit in row
      const int cg = (p ^ (r & 7)) * 8;      // pre-swizzled source column (elems)
      gld16(Ab + (long)(row0 + r) * lda + (k0 + cg), &At[r][p * 8]);
      gld16(Bb + (long)(col0 + r) * ldb + (k0 + cg), &Bt[r][p * 8]);
    }
    __syncthreads();
#pragma unroll
    for (int kk = 0; kk < 2; ++kk) {
      s16x8 af[4], bf[4];
#pragma unroll
      for (int m = 0; m < 4; ++m)
        af[m] = *(const s16x8*)&At[wm * 64 + m * 16 + lk][((kk * 4 + g) ^ (lk & 7)) * 8];
#pragma unroll
      for (int n = 0; n < 4; ++n)
        bf[n] = *(const s16x8*)&Bt[wn * 64 + n * 16 + lk][((kk * 4 + g) ^ (lk & 7)) * 8];
#pragma unroll
      for (int m = 0; m < 4; ++m)
#pragma unroll
        for (int n = 0; n < 4; ++n)
          acc[m][n] = __builtin_amdgcn_mfma_f32_16x16x32_bf16(af[m], bf[n], acc[m][n], 0, 0, 0);
    }
    __syncthreads();
  }

  const float* rz = (EPI == 1) ? rinv + (long)z * 2048 : nullptr;
#pragma unroll
  for (int m = 0; m < 4; ++m) {
    const int grow = row0 + wm * 64 + m * 16 + g * 4;
#pragma unroll
    for (int r = 0; r < 4; ++r) {
      float iv = 0.0f;
      if constexpr (EPI == 1) iv = rz[grow + r];
#pragma unroll
      for (int n = 0; n < 4; ++n) {
        const int gcol = col0 + wn * 64 + n * 16 + lk;
        float v;
        if constexpr (EPI == 1) v = __expf(alpha * acc[m][n][r]) * iv;
        else                    v = alpha * acc[m][n][r] + (bz ? bz[gcol] : 0.0f);
        if constexpr (sizeof(OutT) == 2) C[(long)(grow + r) * ldc + gcol] = f2bf(v);
        else                             C[(long)(grow + r) * ldc + gcol] = v;
      }
    }
  }
}

// ---------------- flash attention: ctx[b,s,h*64+d], rinv[bh,q] = 1/sum(exp) ----------------
// grid (S/128, B*H); 4 waves: wk = wid>>1 (k-half), wq = wid&1 (q-half).
// St[k][q] via mfma(K,Q) so P rows feed PV's B operand directly from registers.
// Q/K tiles: swizzled like the GEMM (contiguous-k8 frags). V tile [64][128]:
// 16B-unit swizzle on low 3 bits of unit index; PV A-frag keeps two-half k
// layout (matches P's register layout), read with swizzle-aware lo/hi b64.
__global__ __launch_bounds__(256) void k_flash(
    const u16* __restrict__ qp, const u16* __restrict__ kp, const u16* __restrict__ vt,
    u16* __restrict__ ctx, float* __restrict__ rinv) {
  __shared__ __align__(16) char lds[49152];
  u16* Qt = (u16*)lds;            // [128][64]
  u16* Kt = (u16*)(lds + 16384);  // [128][64]
  u16* Vl = (u16*)(lds + 32768);  // [64][128]
  const int tid = threadIdx.x, lane = tid & 63, wid = tid >> 6;
  const int wk = wid >> 1, wq = wid & 1;
  const int bh = blockIdx.y, q0 = blockIdx.x * 128;
  const long qkbase = (long)(bh >> 4) * 2097152 + (long)(bh & 15) * 64;
  const long vbase = (long)bh * 131072;
  const int lk = lane & 15, g = lane >> 4;
  const int sp = lane & 7;                  // physical unit for Q/K staging
  const int sr = lane >> 3;

#pragma unroll
  for (int i = 0; i < 4; ++i) {
    const int rr = (wid * 4 + i) * 8 + sr;
    gld16(qp + qkbase + (long)(q0 + rr) * 1024 + ((sp ^ (rr & 7)) * 8), Qt + rr * 64 + sp * 8);
  }
  __syncthreads();

  s16x8 qf[2][4];
#pragma unroll
  for (int kk = 0; kk < 2; ++kk) {
#pragma unroll
    for (int nq = 0; nq < 4; ++nq)
      qf[kk][nq] = *(const s16x8*)(Qt + (wq * 64 + nq * 16 + lk) * 64 + ((kk * 4 + g) ^ (lk & 7)) * 8);
  }

  f32x4 cacc[4][4] = {};
  float rs[4] = {0.f, 0.f, 0.f, 0.f};

  for (int t = 0; t < 16; ++t) {
    const int kb = t * 128;
#pragma unroll
    for (int i = 0; i < 4; ++i) {
      const int rr = (wid * 4 + i) * 8 + sr;
      gld16(kp + qkbase + (long)(kb + rr) * 1024 + ((sp ^ (rr & 7)) * 8), Kt + rr * 64 + sp * 8);
      const int dd = (wid * 4 + i) * 4 + g;
      const int pv = lane & 15;                           // physical 16B unit (0..15)
      const int cv = (pv & 8) | ((pv ^ dd) & 7);          // swizzled source unit
      gld16(vt + vbase + (long)dd * 2048 + (kb + cv * 8), Vl + dd * 128 + pv * 8);
    }
    __syncthreads();

    f32x4 st[4][4] = {};
#pragma unroll
    for (int kk = 0; kk < 2; ++kk) {
      s16x8 af[4];
#pragma unroll
      for (int mk = 0; mk < 4; ++mk)
        af[mk] = *(const s16x8*)(Kt + (wk * 64 + mk * 16 + lk) * 64 + ((kk * 4 + g) ^ (lk & 7)) * 8);
#pragma unroll
      for (int mk = 0; mk < 4; ++mk)
#pragma unroll
        for (int nq = 0; nq < 4; ++nq)
          st[mk][nq] = __builtin_amdgcn_mfma_f32_16x16x32_bf16(af[mk], qf[kk][nq], st[mk][nq], 0, 0, 0);
    }
#pragma unroll
    for (int mk = 0; mk < 4; ++mk)
#pragma unroll
      for (int nq = 0; nq < 4; ++nq)
#pragma unroll
        for (int j = 0; j < 4; ++j) {
          const float p = __expf(st[mk][nq][j] * 0.125f);
          st[mk][nq][j] = p;
          rs[nq] += p;
        }
#pragma unroll
    for (int ks = 0; ks < 2; ++ks) {
      s16x8 pb[4];
#pragma unroll
      for (int nq = 0; nq < 4; ++nq) {
        s16x8 b;
#pragma unroll
        for (int j = 0; j < 4; ++j) {
          b[j]     = (short)f2bf(st[2 * ks][nq][j]);
          b[4 + j] = (short)f2bf(st[2 * ks + 1][nq][j]);
        }
        pb[nq] = b;
      }
#pragma unroll
      for (int md = 0; md < 4; ++md) {
        const int rowv = md * 16 + lk;
        const int u0 = ks * 4 + (g >> 1);                       // lo unit (low-3 domain)
        const int p0 = wk * 8 + ((u0 ^ (rowv & 7)) & 7);
        const int p2 = wk * 8 + (((u0 + 2) ^ (rowv & 7)) & 7);  // hi unit (+16 elems)
        const u16* vb0 = Vl + rowv * 128 + p0 * 8 + (g & 1) * 4;
        const u16* vb2 = Vl + rowv * 128 + p2 * 8 + (g & 1) * 4;
        s16x4 lo = *(const s16x4*)vb0;
        s16x4 hi = *(const s16x4*)vb2;
        s16x8 vf;
        vf[0] = lo[0]; vf[1] = lo[1]; vf[2] = lo[2]; vf[3] = lo[3];
        vf[4] = hi[0]; vf[5] = hi[1]; vf[6] = hi[2]; vf[7] = hi[3];
#pragma unroll
        for (int nq = 0; nq < 4; ++nq)
          cacc[md][nq] = __builtin_amdgcn_mfma_f32_16x16x32_bf16(vf, pb[nq], cacc[md][nq], 0, 0, 0);
      }
    }
    __syncthreads();
  }

#pragma unroll
  for (int nq = 0; nq < 4; ++nq) {
    rs[nq] += __shfl_xor(rs[nq], 16, 64);
    rs[nq] += __shfl_xor(rs[nq], 32, 64);
  }
  float* ctxl = (float*)lds;            // [64][129]
  float* rsl  = (float*)(lds + 33024);  // [128]
  if (wk == 1) {
#pragma unroll
    for (int md = 0; md < 4; ++md)
#pragma unroll
      for (int nq = 0; nq < 4; ++nq)
#pragma unroll
        for (int r = 0; r < 4; ++r)
          ctxl[(md * 16 + g * 4 + r) * 129 + wq * 64 + nq * 16 + lk] = cacc[md][nq][r];
    if (lane < 16)
#pragma unroll
      for (int nq = 0; nq < 4; ++nq) rsl[wq * 64 + nq * 16 + lane] = rs[nq];
  }
  __syncthreads();
  if (wk == 0) {
#pragma unroll
    for (int md = 0; md < 4; ++md)
#pragma unroll
      for (int nq = 0; nq < 4; ++nq)
#pragma unroll
        for (int r = 0; r < 4; ++r) {
          const int idx = (md * 16 + g * 4 + r) * 129 + wq * 64 + nq * 16 + lk;
          ctxl[idx] += cacc[md][nq][r];
        }
    if (lane < 16)
#pragma unroll
      for (int nq = 0; nq < 4; ++nq) {
        const int qi = wq * 64 + nq * 16 + lane;
        const float inv = 1.0f / (rsl[qi] + rs[nq]);
        rsl[qi] = inv;
        rinv[(long)bh * 2048 + q0 + qi] = inv;
      }
  }
  __syncthreads();
  // cooperative transposed write: ctx[b][q0+qr][h*64 + d]
  const int qr = tid >> 1, half = tid & 1;
  const float inv = rsl[qr];
  u16* dst = ctx + (long)(bh >> 4) * 2097152 + (long)(q0 + qr) * 1024 + (long)(bh & 15) * 64 + half * 32;
#pragma unroll
  for (int c = 0; c < 4; ++c) {
    s16x8 o;
#pragma unroll
    for (int j = 0; j < 8; ++j) {
      const int d = half * 32 + c * 8 + j;
      o[j] = (short)f2bf(ctxl[d * 129 + qr] * inv);
    }
    ((s16x8*)dst)[c] = o;
  }
}

// ---------------- in-place row softmax, rows of 2048 fp32 ----------------
__global__ __launch_bounds__(256) void k_softmax(float* __restrict__ base) {
  float* p = base + (long)blockIdx.x * 2048;
  const int t = threadIdx.x;
  float4 v0 = ((const float4*)p)[t];
  float4 v1 = ((const float4*)p)[t + 256];
  float m = fmaxf(fmaxf(fmaxf(v0.x, v0.y), fmaxf(v0.z, v0.w)),
                  fmaxf(fmaxf(v1.x, v1.y), fmaxf(v1.z, v1.w)));
#pragma unroll
  for (int i = 32; i >= 1; i >>= 1) m = fmaxf(m, __shfl_xor(m, i, 64));
  __shared__ float sm[4], ss[4];
  if ((t & 63) == 0) sm[t >> 6] = m;
  __syncthreads();
  m = fmaxf(fmaxf(sm[0], sm[1]), fmaxf(sm[2], sm[3]));
  float4 e0, e1;
  e0.x = __expf(v0.x - m); e0.y = __expf(v0.y - m); e0.z = __expf(v0.z - m); e0.w = __expf(v0.w - m);
  e1.x = __expf(v1.x - m); e1.y = __expf(v1.y - m); e1.z = __expf(v1.z - m); e1.w = __expf(v1.w - m);
  float s = (e0.x + e0.y + e0.z + e0.w) + (e1.x + e1.y + e1.z + e1.w);
#pragma unroll
  for (int i = 32; i >= 1; i >>= 1) s += __shfl_xor(s, i, 64);
  if ((t & 63) == 0) ss[t >> 6] = s;
  __syncthreads();
  s = ss[0] + ss[1] + ss[2] + ss[3];
  float inv = 1.0f / s;
  e0.x *= inv; e0.y *= inv; e0.z *= inv; e0.w *= inv;
  e1.x *= inv; e1.y *= inv; e1.z *= inv; e1.w *= inv;
  ((float4*)p)[t] = e0;
  ((float4*)p)[t + 256] = e1;
}

// ---------------- launch ----------------
extern "C" void kernel_launch(void* const* d_in, const int* in_sizes, int n_in,
                              void* d_out, int out_size, void* d_ws, size_t ws_size,
                              hipStream_t stream) {
  const float* query = (const float*)d_in[0];
  const float* key   = (const float*)d_in[1];
  const float* value = (const float*)d_in[2];
  const float* Wq = (const float*)d_in[3];
  const float* bq = (const float*)d_in[4];
  const float* Wk = (const float*)d_in[5];
  const float* bk = (const float*)d_in[6];
  const float* Wv = (const float*)d_in[7];
  const float* bv = (const float*)d_in[8];
  const float* Wo = (const float*)d_in[9];
  const float* bo = (const float*)d_in[10];
  const float* Wa = (const float*)d_in[11];
  const float* ba = (const float*)d_in[12];
  float* out = (float*)d_out;
  char* ws = (char*)d_ws;

  // workspace layout (bytes)
  u16* qb  = (u16*)(ws + 0);           // [4096,1024] bf16 query
  u16* kb  = (u16*)(ws + 8388608);
  u16* vb  = (u16*)(ws + 16777216);
  u16* Wqt = (u16*)(ws + 25165824);    // [1024,1024] W^T bf16 (reused as rinv later)
  u16* Wkt = (u16*)(ws + 27262976);
  u16* Wvt = (u16*)(ws + 29360128);
  u16* Wot = (u16*)(ws + 31457280);
  u16* Wat = (u16*)(ws + 33554432);    // [3,1024,1024]
  u16* qp  = (u16*)(ws + 39845888);    // [4096,1024] projected q
  u16* kp  = (u16*)(ws + 48234496);
  u16* vp  = (u16*)(ws + 56623104);
  u16* vt  = (u16*)(ws + 65011712);    // [B,H,64,2048] V^T per head
  u16* ctx = (u16*)(ws + 73400320);    // [4096,1024]
  u16* qa  = (u16*)(ws + 81788928);    // [3,4096,1024] aspect q
  u16* ka  = (u16*)(ws + 106954752);   // [3,4096,1024] aspect k
  float* rinv = (float*)(ws + 25165824);  // [32,2048] (overwrites Wqt after use)

  dim3 b256(256);
  dim3 trb(32, 8);

  // bf16 conversions of activations
  k_cvt<<<4096, b256, 0, stream>>>(query, qb, 1048576);
  k_cvt<<<4096, b256, 0, stream>>>(key,   kb, 1048576);
  k_cvt<<<4096, b256, 0, stream>>>(value, vb, 1048576);

  // weight transposes (fp32 -> bf16, [N,K])
  k_tr<true><<<dim3(32, 32, 1), trb, 0, stream>>>(Wq, Wqt, 1024, 1024, 0, 0, 0, 1);
  k_tr<true><<<dim3(32, 32, 1), trb, 0, stream>>>(Wk, Wkt, 1024, 1024, 0, 0, 0, 1);
  k_tr<true><<<dim3(32, 32, 1), trb, 0, stream>>>(Wv, Wvt, 1024, 1024, 0, 0, 0, 1);
  k_tr<true><<<dim3(32, 32, 1), trb, 0, stream>>>(Wo, Wot, 1024, 1024, 0, 0, 0, 1);
  k_tr<true><<<dim3(32, 32, 3), trb, 0, stream>>>(Wa, Wat, 1024, 1024, 0, 1048576, 1048576, 3);

  // Q/K/V projections -> bf16 [4096,1024]   (Q first: frees Wqt slot for rinv)
  k_gemm_nt<u16, 0><<<dim3(8, 32, 1), b256, 0, stream>>>(
      qb, Wqt, qp, bq, nullptr, 1.0f, 1024, 1024, 1024, 1024, 0, 0, 0, 0, 0, 0, 0, 1);
  k_gemm_nt<u16, 0><<<dim3(8, 32, 1), b256, 0, stream>>>(
      kb, Wkt, kp, bk, nullptr, 1.0f, 1024, 1024, 1024, 1024, 0, 0, 0, 0, 0, 0, 0, 1);
  k_gemm_nt<u16, 0><<<dim3(8, 32, 1), b256, 0, stream>>>(
      vb, Wvt, vp, bv, nullptr, 1.0f, 1024, 1024, 1024, 1024, 0, 0, 0, 0, 0, 0, 0, 1);

  // aspect projections, z = aspect (3)
  k_gemm_nt<u16, 0><<<dim3(8, 32, 3), b256, 0, stream>>>(
      qb, Wat, qa, ba, nullptr, 1.0f, 1024, 1024, 1024, 1024,
      0, 0, 0, 1048576, 0, 4194304, 1024, 3);
  k_gemm_nt<u16, 0><<<dim3(8, 32, 3), b256, 0, stream>>>(
      kb, Wat, ka, ba, nullptr, 1.0f, 1024, 1024, 1024, 1024,
      0, 0, 0, 1048576, 0, 4194304, 1024, 3);

  // per-head V^T: vt[b,h][d][s]  (z = b*16+h)
  k_tr<false><<<dim3(2, 64, 32), trb, 0, stream>>>(
      vp, vt, 1024, 2048, 2097152, 64, 131072, 16);

  // flash attention: ctx (bf16) + rinv
  k_flash<<<dim3(16, 32), b256, 0, stream>>>(qp, kp, vt, ctx, rinv);

  // attn_weights = exp(QK^T * scale) * rinv  -> d_out (single write pass)
  k_gemm_nt<float, 1><<<dim3(16, 16, 32), b256, 0, stream>>>(
      qp, kp, out + AW_OFF, nullptr, rinv, 0.125f, 64, 1024, 1024, 2048,
      2097152, 64, 2097152, 64, 67108864, 4194304, 0, 16);

  // full-dim pattern logits -> d_out patterns region (z = a*2+b)
  k_gemm_nt<float, 0><<<dim3(16, 16, 6), b256, 0, stream>>>(
      qa, ka, out + PAT_OFF, nullptr, nullptr, 0.125f, 1024, 1024, 1024, 2048,
      0, 2097152, 0, 2097152, 0, 4194304, 0, 6);

  // softmax over patterns only (3*B*S = 12288 rows of 2048)
  k_softmax<<<12288, b256, 0, stream>>>(out + PAT_OFF);

  // output projection -> d_out attn_output
  k_gemm_nt<float, 0><<<dim3(8, 32, 1), b256, 0, stream>>>(
      ctx, Wot, out, bo, nullptr, 1.0f, 1024, 1024, 1024, 1024, 0, 0, 0, 0, 0, 0, 0, 1);
}

// Round 5
// 509.510 us; speedup vs baseline: 2.7617x; 1.1076x over previous
//
#include <hip/hip_runtime.h>

typedef unsigned short u16;
typedef short s16x4 __attribute__((ext_vector_type(4)));
typedef short s16x8 __attribute__((ext_vector_type(8)));
typedef float f32x4 __attribute__((ext_vector_type(4)));

#define DEVFN __device__ __forceinline__

// problem constants
constexpr long AW_OFF  = 4194304;               // attn_output elems (2*2048*1024)
constexpr long PAT_OFF = AW_OFF + 134217728;    // + attn_weights elems (2*16*2048*2048)

DEVFN u16 f2bf(float x) {
  unsigned u = __builtin_bit_cast(unsigned, x);
  unsigned r = (u + 0x7fffu + ((u >> 16) & 1u)) >> 16;   // RNE
  return (u16)r;
}

DEVFN void gld16(const u16* g, u16* l) {
  __builtin_amdgcn_global_load_lds(
      (const __attribute__((address_space(1))) unsigned int*)g,
      (__attribute__((address_space(3))) unsigned int*)l, 16, 0, 0);
}

// ---------------- fp32 -> bf16 elementwise, 3 tensors ----------------
__global__ __launch_bounds__(256) void k_cvt3(const float* __restrict__ a,
                                              const float* __restrict__ b,
                                              const float* __restrict__ c,
                                              u16* __restrict__ out, int n4) {
  int i = blockIdx.x * 256 + threadIdx.x;
  if (i >= n4) return;
  const float* in = (blockIdx.y == 0) ? a : (blockIdx.y == 1) ? b : c;
  float4 v = ((const float4*)in)[i];
  s16x4 o; o[0] = f2bf(v.x); o[1] = f2bf(v.y); o[2] = f2bf(v.z); o[3] = f2bf(v.w);
  ((s16x4*)(out + (long)blockIdx.y * 4194304))[i] = o;
}

// ---------------- pack 3 bias vectors contiguous ----------------
__global__ __launch_bounds__(256) void k_pack3(const float* __restrict__ a,
                                               const float* __restrict__ b,
                                               const float* __restrict__ c,
                                               float* __restrict__ out) {
  int i = blockIdx.x * 256 + threadIdx.x;   // grid 12 -> 3072
  const float* in = (i < 1024) ? a : (i < 2048) ? b : c;
  out[i] = in[i & 1023];
}

// ---------------- tiled transpose: out[n][k] = bf16(in[k][n]) ----------------
template <bool IN_F32>
__global__ __launch_bounds__(256) void k_tr(const void* __restrict__ inv,
                                            u16* __restrict__ out,
                                            long ldin, long ldout,
                                            long inz1, long inz2, long outz, int zdiv) {
  __shared__ u16 tile[32][33];
  int z = blockIdx.z;
  long ioff = (long)(z / zdiv) * inz1 + (long)(z % zdiv) * inz2;
  int k0 = blockIdx.y * 32, n0 = blockIdx.x * 32;
  int tx = threadIdx.x, ty = threadIdx.y;
#pragma unroll
  for (int i = 0; i < 4; ++i) {
    long k = k0 + ty + i * 8, n = n0 + tx;
    u16 v;
    if constexpr (IN_F32) v = f2bf(((const float*)inv)[ioff + k * ldin + n]);
    else                  v = ((const u16*)inv)[ioff + k * ldin + n];
    tile[ty + i * 8][tx] = v;
  }
  __syncthreads();
  long ooff = (long)z * outz;
#pragma unroll
  for (int i = 0; i < 4; ++i) {
    long n = n0 + ty + i * 8, k = k0 + tx;
    out[ooff + n * ldout + k] = tile[tx][ty + i * 8];
  }
}

// ---------------- batched NT GEMM: C = f(alpha * A[M,K] @ B[N,K]^T) ----------------
// EPI 0: v = alpha*acc + bias[z2][col];  EPI 1: v = exp(alpha*acc) * rinv[z][row]
// global_load_lds staging, LINEAR LDS dest + XOR-swizzled (p = c ^ (row&7), 16B units)
// global source and fragment reads -> conflict-free ds_read_b128 fragments.
// XCD-chunked bijective block swizzle (nb%8==0) for per-XCD L2 locality.
template <typename OutT, int EPI>
__global__ __launch_bounds__(256) void k_gemm_nt(
    const u16* __restrict__ Ap, const u16* __restrict__ Bp, OutT* __restrict__ Cp,
    const float* __restrict__ bias, const float* __restrict__ rinv, float alpha, int K,
    long lda, long ldb, long ldc,
    long saz1, long saz2, long sbz1, long sbz2, long scz1, long scz2,
    long sbias, int zdiv) {
  __shared__ __align__(16) u16 At[128][64];
  __shared__ __align__(16) u16 Bt[128][64];
  const int tid = threadIdx.x, lane = tid & 63, wid = tid >> 6;
  const int wm = wid >> 1, wn = wid & 1;

  // XCD swizzle: hardware XCD = linear_id % 8; give each XCD a contiguous chunk.
  const int gx = gridDim.x, gy = gridDim.y;
  int id = (blockIdx.z * gy + blockIdx.y) * gx + blockIdx.x;
  const int nb = gx * gy * (int)gridDim.z;
  if ((nb & 7) == 0) id = (id & 7) * (nb >> 3) + (id >> 3);
  const int bxi = id % gx, byi = (id / gx) % gy, bzi = id / (gx * gy);

  const int z = bzi, z1 = z / zdiv, z2 = z % zdiv;
  const u16* Ab = Ap + (long)z1 * saz1 + (long)z2 * saz2;
  const u16* Bb = Bp + (long)z1 * sbz1 + (long)z2 * sbz2;
  OutT* C = Cp + (long)z1 * scz1 + (long)z2 * scz2;
  const float* bv = bias ? bias + (long)z2 * sbias : nullptr;
  const int row0 = byi * 128, col0 = bxi * 128;
  const int lk = lane & 15, g = lane >> 4;

  f32x4 acc[4][4] = {};

  for (int k0 = 0; k0 < K; k0 += 64) {
#pragma unroll
    for (int it = 0; it < 4; ++it) {
      const int u = it * 256 + tid;          // 16B-unit index over the tile
      const int r = u >> 3, p = u & 7;       // row, physical unit in row
      const int cg = (p ^ (r & 7)) * 8;      // pre-swizzled source column (elems)
      gld16(Ab + (long)(row0 + r) * lda + (k0 + cg), &At[r][p * 8]);
      gld16(Bb + (long)(col0 + r) * ldb + (k0 + cg), &Bt[r][p * 8]);
    }
    __syncthreads();
#pragma unroll
    for (int kk = 0; kk < 2; ++kk) {
      s16x8 af[4], bf[4];
#pragma unroll
      for (int m = 0; m < 4; ++m)
        af[m] = *(const s16x8*)&At[wm * 64 + m * 16 + lk][((kk * 4 + g) ^ (lk & 7)) * 8];
#pragma unroll
      for (int n = 0; n < 4; ++n)
        bf[n] = *(const s16x8*)&Bt[wn * 64 + n * 16 + lk][((kk * 4 + g) ^ (lk & 7)) * 8];
#pragma unroll
      for (int m = 0; m < 4; ++m)
#pragma unroll
        for (int n = 0; n < 4; ++n)
          acc[m][n] = __builtin_amdgcn_mfma_f32_16x16x32_bf16(af[m], bf[n], acc[m][n], 0, 0, 0);
    }
    __syncthreads();
  }

  const float* rz = (EPI == 1) ? rinv + (long)z * 2048 : nullptr;
#pragma unroll
  for (int m = 0; m < 4; ++m) {
    const int grow = row0 + wm * 64 + m * 16 + g * 4;
#pragma unroll
    for (int r = 0; r < 4; ++r) {
      float iv = 0.0f;
      if constexpr (EPI == 1) iv = rz[grow + r];
#pragma unroll
      for (int n = 0; n < 4; ++n) {
        const int gcol = col0 + wn * 64 + n * 16 + lk;
        float v;
        if constexpr (EPI == 1) v = __expf(alpha * acc[m][n][r]) * iv;
        else                    v = alpha * acc[m][n][r] + (bv ? bv[gcol] : 0.0f);
        if constexpr (sizeof(OutT) == 2) C[(long)(grow + r) * ldc + gcol] = f2bf(v);
        else                             C[(long)(grow + r) * ldc + gcol] = v;
      }
    }
  }
}

// ---------------- flash attention: ctx[b,s,h*64+d], rinv[bh,q] = 1/sum(exp) ----------------
// grid (S/128, B*H); 4 waves: wk = wid>>1 (k-half), wq = wid&1 (q-half).
// St[k][q] via mfma(K,Q) so P rows feed PV's B operand directly from registers.
__global__ __launch_bounds__(256) void k_flash(
    const u16* __restrict__ qp, const u16* __restrict__ kp, const u16* __restrict__ vt,
    u16* __restrict__ ctx, float* __restrict__ rinv) {
  __shared__ __align__(16) char lds[49152];
  u16* Qt = (u16*)lds;            // [128][64]
  u16* Kt = (u16*)(lds + 16384);  // [128][64]
  u16* Vl = (u16*)(lds + 32768);  // [64][128]
  const int tid = threadIdx.x, lane = tid & 63, wid = tid >> 6;
  const int wk = wid >> 1, wq = wid & 1;

  // XCD swizzle: each XCD gets 4 consecutive heads (512/8 = 64 = 4 heads x 16 q-blocks)
  const int gx = gridDim.x;
  int id = blockIdx.y * gx + blockIdx.x;
  const int nb = gx * (int)gridDim.y;
  if ((nb & 7) == 0) id = (id & 7) * (nb >> 3) + (id >> 3);
  const int bh = id / gx, q0 = (id % gx) * 128;

  const long qkbase = (long)(bh >> 4) * 2097152 + (long)(bh & 15) * 64;
  const long vbase = (long)bh * 131072;
  const int lk = lane & 15, g = lane >> 4;
  const int sp = lane & 7;                  // physical unit for Q/K staging
  const int sr = lane >> 3;

#pragma unroll
  for (int i = 0; i < 4; ++i) {
    const int rr = (wid * 4 + i) * 8 + sr;
    gld16(qp + qkbase + (long)(q0 + rr) * 1024 + ((sp ^ (rr & 7)) * 8), Qt + rr * 64 + sp * 8);
  }
  __syncthreads();

  s16x8 qf[2][4];
#pragma unroll
  for (int kk = 0; kk < 2; ++kk) {
#pragma unroll
    for (int nq = 0; nq < 4; ++nq)
      qf[kk][nq] = *(const s16x8*)(Qt + (wq * 64 + nq * 16 + lk) * 64 + ((kk * 4 + g) ^ (lk & 7)) * 8);
  }

  f32x4 cacc[4][4] = {};
  float rs[4] = {0.f, 0.f, 0.f, 0.f};

  for (int t = 0; t < 16; ++t) {
    const int kb = t * 128;
#pragma unroll
    for (int i = 0; i < 4; ++i) {
      const int rr = (wid * 4 + i) * 8 + sr;
      gld16(kp + qkbase + (long)(kb + rr) * 1024 + ((sp ^ (rr & 7)) * 8), Kt + rr * 64 + sp * 8);
      const int dd = (wid * 4 + i) * 4 + g;
      const int pv = lane & 15;                           // physical 16B unit (0..15)
      const int cv = (pv & 8) | ((pv ^ dd) & 7);          // swizzled source unit
      gld16(vt + vbase + (long)dd * 2048 + (kb + cv * 8), Vl + dd * 128 + pv * 8);
    }
    __syncthreads();

    f32x4 st[4][4] = {};
#pragma unroll
    for (int kk = 0; kk < 2; ++kk) {
      s16x8 af[4];
#pragma unroll
      for (int mk = 0; mk < 4; ++mk)
        af[mk] = *(const s16x8*)(Kt + (wk * 64 + mk * 16 + lk) * 64 + ((kk * 4 + g) ^ (lk & 7)) * 8);
#pragma unroll
      for (int mk = 0; mk < 4; ++mk)
#pragma unroll
        for (int nq = 0; nq < 4; ++nq)
          st[mk][nq] = __builtin_amdgcn_mfma_f32_16x16x32_bf16(af[mk], qf[kk][nq], st[mk][nq], 0, 0, 0);
    }
#pragma unroll
    for (int mk = 0; mk < 4; ++mk)
#pragma unroll
      for (int nq = 0; nq < 4; ++nq)
#pragma unroll
        for (int j = 0; j < 4; ++j) {
          const float p = __expf(st[mk][nq][j] * 0.125f);
          st[mk][nq][j] = p;
          rs[nq] += p;
        }
#pragma unroll
    for (int ks = 0; ks < 2; ++ks) {
      s16x8 pb[4];
#pragma unroll
      for (int nq = 0; nq < 4; ++nq) {
        s16x8 b;
#pragma unroll
        for (int j = 0; j < 4; ++j) {
          b[j]     = (short)f2bf(st[2 * ks][nq][j]);
          b[4 + j] = (short)f2bf(st[2 * ks + 1][nq][j]);
        }
        pb[nq] = b;
      }
#pragma unroll
      for (int md = 0; md < 4; ++md) {
        const int rowv = md * 16 + lk;
        const int u0 = ks * 4 + (g >> 1);                       // lo unit (low-3 domain)
        const int p0 = wk * 8 + ((u0 ^ (rowv & 7)) & 7);
        const int p2 = wk * 8 + (((u0 + 2) ^ (rowv & 7)) & 7);  // hi unit (+16 elems)
        const u16* vb0 = Vl + rowv * 128 + p0 * 8 + (g & 1) * 4;
        const u16* vb2 = Vl + rowv * 128 + p2 * 8 + (g & 1) * 4;
        s16x4 lo = *(const s16x4*)vb0;
        s16x4 hi = *(const s16x4*)vb2;
        s16x8 vf;
        vf[0] = lo[0]; vf[1] = lo[1]; vf[2] = lo[2]; vf[3] = lo[3];
        vf[4] = hi[0]; vf[5] = hi[1]; vf[6] = hi[2]; vf[7] = hi[3];
#pragma unroll
        for (int nq = 0; nq < 4; ++nq)
          cacc[md][nq] = __builtin_amdgcn_mfma_f32_16x16x32_bf16(vf, pb[nq], cacc[md][nq], 0, 0, 0);
      }
    }
    __syncthreads();
  }

#pragma unroll
  for (int nq = 0; nq < 4; ++nq) {
    rs[nq] += __shfl_xor(rs[nq], 16, 64);
    rs[nq] += __shfl_xor(rs[nq], 32, 64);
  }
  float* ctxl = (float*)lds;            // [64][129]
  float* rsl  = (float*)(lds + 33024);  // [128]
  if (wk == 1) {
#pragma unroll
    for (int md = 0; md < 4; ++md)
#pragma unroll
      for (int nq = 0; nq < 4; ++nq)
#pragma unroll
        for (int r = 0; r < 4; ++r)
          ctxl[(md * 16 + g * 4 + r) * 129 + wq * 64 + nq * 16 + lk] = cacc[md][nq][r];
    if (lane < 16)
#pragma unroll
      for (int nq = 0; nq < 4; ++nq) rsl[wq * 64 + nq * 16 + lane] = rs[nq];
  }
  __syncthreads();
  if (wk == 0) {
#pragma unroll
    for (int md = 0; md < 4; ++md)
#pragma unroll
      for (int nq = 0; nq < 4; ++nq)
#pragma unroll
        for (int r = 0; r < 4; ++r) {
          const int idx = (md * 16 + g * 4 + r) * 129 + wq * 64 + nq * 16 + lk;
          ctxl[idx] += cacc[md][nq][r];
        }
    if (lane < 16)
#pragma unroll
      for (int nq = 0; nq < 4; ++nq) {
        const int qi = wq * 64 + nq * 16 + lane;
        const float inv = 1.0f / (rsl[qi] + rs[nq]);
        rsl[qi] = inv;
        rinv[(long)bh * 2048 + q0 + qi] = inv;
      }
  }
  __syncthreads();
  // cooperative transposed write: ctx[b][q0+qr][h*64 + d]
  const int qr = tid >> 1, half = tid & 1;
  const float inv = rsl[qr];
  u16* dst = ctx + (long)(bh >> 4) * 2097152 + (long)(q0 + qr) * 1024 + (long)(bh & 15) * 64 + half * 32;
#pragma unroll
  for (int c = 0; c < 4; ++c) {
    s16x8 o;
#pragma unroll
    for (int j = 0; j < 8; ++j) {
      const int d = half * 32 + c * 8 + j;
      o[j] = (short)f2bf(ctxl[d * 129 + qr] * inv);
    }
    ((s16x8*)dst)[c] = o;
  }
}

// ---------------- in-place row softmax, rows of 2048 fp32 ----------------
__global__ __launch_bounds__(256) void k_softmax(float* __restrict__ base) {
  float* p = base + (long)blockIdx.x * 2048;
  const int t = threadIdx.x;
  float4 v0 = ((const float4*)p)[t];
  float4 v1 = ((const float4*)p)[t + 256];
  float m = fmaxf(fmaxf(fmaxf(v0.x, v0.y), fmaxf(v0.z, v0.w)),
                  fmaxf(fmaxf(v1.x, v1.y), fmaxf(v1.z, v1.w)));
#pragma unroll
  for (int i = 32; i >= 1; i >>= 1) m = fmaxf(m, __shfl_xor(m, i, 64));
  __shared__ float sm[4], ss[4];
  if ((t & 63) == 0) sm[t >> 6] = m;
  __syncthreads();
  m = fmaxf(fmaxf(sm[0], sm[1]), fmaxf(sm[2], sm[3]));
  float4 e0, e1;
  e0.x = __expf(v0.x - m); e0.y = __expf(v0.y - m); e0.z = __expf(v0.z - m); e0.w = __expf(v0.w - m);
  e1.x = __expf(v1.x - m); e1.y = __expf(v1.y - m); e1.z = __expf(v1.z - m); e1.w = __expf(v1.w - m);
  float s = (e0.x + e0.y + e0.z + e0.w) + (e1.x + e1.y + e1.z + e1.w);
#pragma unroll
  for (int i = 32; i >= 1; i >>= 1) s += __shfl_xor(s, i, 64);
  if ((t & 63) == 0) ss[t >> 6] = s;
  __syncthreads();
  s = ss[0] + ss[1] + ss[2] + ss[3];
  float inv = 1.0f / s;
  e0.x *= inv; e0.y *= inv; e0.z *= inv; e0.w *= inv;
  e1.x *= inv; e1.y *= inv; e1.z *= inv; e1.w *= inv;
  ((float4*)p)[t] = e0;
  ((float4*)p)[t + 256] = e1;
}

// ---------------- launch ----------------
extern "C" void kernel_launch(void* const* d_in, const int* in_sizes, int n_in,
                              void* d_out, int out_size, void* d_ws, size_t ws_size,
                              hipStream_t stream) {
  const float* query = (const float*)d_in[0];
  const float* key   = (const float*)d_in[1];
  const float* value = (const float*)d_in[2];
  const float* Wq = (const float*)d_in[3];
  const float* bq = (const float*)d_in[4];
  const float* Wk = (const float*)d_in[5];
  const float* bk = (const float*)d_in[6];
  const float* Wv = (const float*)d_in[7];
  const float* bv = (const float*)d_in[8];
  const float* Wo = (const float*)d_in[9];
  const float* bo = (const float*)d_in[10];
  const float* Wa = (const float*)d_in[11];
  const float* ba = (const float*)d_in[12];
  float* out = (float*)d_out;
  char* ws = (char*)d_ws;

  // workspace layout (bytes)
  u16* qb  = (u16*)(ws + 0);           // [3][4096,1024] bf16 q,k,v (contiguous)
  u16* Wqt = (u16*)(ws + 25165824);    // [3][1024,1024] Wq^T,Wk^T,Wv^T bf16 (contig; reused as rinv)
  u16* Wot = (u16*)(ws + 31457280);
  u16* Wat = (u16*)(ws + 33554432);    // [3,1024,1024]
  u16* qp  = (u16*)(ws + 39845888);    // [3][4096,1024] projected q,k,v (contiguous)
  u16* kp  = (u16*)(ws + 48234496);
  u16* vp  = (u16*)(ws + 56623104);
  u16* vt  = (u16*)(ws + 65011712);    // [B,H,64,2048] V^T per head
  u16* ctx = (u16*)(ws + 73400320);    // [4096,1024]
  u16* qa  = (u16*)(ws + 81788928);    // [2][3][4096,1024] aspect q then aspect k (contiguous)
  float* rinv  = (float*)(ws + 25165824);   // [32,2048] (overwrites Wqt after proj)
  float* pbias = (float*)(ws + 132120576);  // [3,1024] packed bq,bk,bv

  dim3 b256(256);
  dim3 trb(32, 8);

  // bf16 conversions of q,k,v activations (one launch)
  k_cvt3<<<dim3(4096, 3), b256, 0, stream>>>(query, key, value, qb, 1048576);
  // pack projection biases contiguous
  k_pack3<<<12, b256, 0, stream>>>(bq, bk, bv, pbias);

  // weight transposes (fp32 -> bf16, [N,K]); Wq/Wk/Wv outputs contiguous
  k_tr<true><<<dim3(32, 32, 1), trb, 0, stream>>>(Wq, Wqt, 1024, 1024, 0, 0, 0, 1);
  k_tr<true><<<dim3(32, 32, 1), trb, 0, stream>>>(Wk, Wqt + 1048576, 1024, 1024, 0, 0, 0, 1);
  k_tr<true><<<dim3(32, 32, 1), trb, 0, stream>>>(Wv, Wqt + 2097152, 1024, 1024, 0, 0, 0, 1);
  k_tr<true><<<dim3(32, 32, 1), trb, 0, stream>>>(Wo, Wot, 1024, 1024, 0, 0, 0, 1);
  k_tr<true><<<dim3(32, 32, 3), trb, 0, stream>>>(Wa, Wat, 1024, 1024, 0, 1048576, 1048576, 3);

  // Q/K/V projections in ONE launch (z = 0,1,2) -> qp,kp,vp
  k_gemm_nt<u16, 0><<<dim3(8, 32, 3), b256, 0, stream>>>(
      qb, Wqt, qp, pbias, nullptr, 1.0f, 1024, 1024, 1024, 1024,
      0, 4194304, 0, 1048576, 0, 4194304, 1024, 3);

  // aspect projections of q and k in ONE launch (z1 = q/k, z2 = aspect)
  k_gemm_nt<u16, 0><<<dim3(8, 32, 6), b256, 0, stream>>>(
      qb, Wat, qa, ba, nullptr, 1.0f, 1024, 1024, 1024, 1024,
      4194304, 0, 0, 1048576, 12582912, 4194304, 1024, 3);

  // per-head V^T: vt[b,h][d][s]  (z = b*16+h)
  k_tr<false><<<dim3(2, 64, 32), trb, 0, stream>>>(
      vp, vt, 1024, 2048, 2097152, 64, 131072, 16);

  // flash attention: ctx (bf16) + rinv
  k_flash<<<dim3(16, 32), b256, 0, stream>>>(qp, kp, vt, ctx, rinv);

  // attn_weights = exp(QK^T * scale) * rinv  -> d_out (single write pass)
  k_gemm_nt<float, 1><<<dim3(16, 16, 32), b256, 0, stream>>>(
      qp, kp, out + AW_OFF, nullptr, rinv, 0.125f, 64, 1024, 1024, 2048,
      2097152, 64, 2097152, 64, 67108864, 4194304, 0, 16);

  // full-dim pattern logits -> d_out patterns region (z = a*2+b)
  k_gemm_nt<float, 0><<<dim3(16, 16, 6), b256, 0, stream>>>(
      qa, qa + 12582912, out + PAT_OFF, nullptr, nullptr, 0.125f, 1024, 1024, 1024, 2048,
      0, 2097152, 0, 2097152, 0, 4194304, 0, 6);

  // softmax over patterns only (3*B*S = 12288 rows of 2048)
  k_softmax<<<12288, b256, 0, stream>>>(out + PAT_OFF);

  // output projection -> d_out attn_output
  k_gemm_nt<float, 0><<<dim3(8, 32, 1), b256, 0, stream>>>(
      ctx, Wot, out, bo, nullptr, 1.0f, 1024, 1024, 1024, 1024, 0, 0, 0, 0, 0, 0, 0, 1);
}